// Round 20
// baseline (5965.369 us; speedup 1.0000x reference)
//
#include <hip/hip_runtime.h>
#include <stdint.h>

// R20 = R19 (PASS, 410us/win) + FUSED GEMM: the recur kernel computes the
// NEXT window's xg during its ~90% idle per-step latency. Evidence: cadence
// 6.4us/step invariant under every protocol change (R10-R19) => latency
// quantum; standalone gemm (0.7ms) can hide inside it. Per step, after the
// cell+h-store, each wave runs a 32-MFMA slice of xg(w+1)=x@Wih+bias (block
// = 128x512 tile; wave = one 16x16 subtile per 2-step K=1024 chain; 64 steps
// cover the tile exactly). Slice doubles as productive backoff before the
// next poll; may also keep DPM clocks up (R18's dead spin never executed).
// x pre-converted per-window to bf16 (8MB dbuf): prologue kernel does window
// 1; recur(w) converts window w+2 (0.5 f32/thread/step). Fallback to plain
// R19 path if ws_size < ~97MB. Everything else byte-identical to R19.

typedef unsigned short u16;
typedef __attribute__((ext_vector_type(8))) short bf16x8;
typedef __attribute__((ext_vector_type(2))) uint64_t u64x2;
typedef __attribute__((ext_vector_type(4))) float f32x4;

#define BAR_LDS()                                        \
  do {                                                   \
    __builtin_amdgcn_sched_barrier(0);                   \
    asm volatile("s_waitcnt lgkmcnt(0)" ::: "memory");   \
    __builtin_amdgcn_s_barrier();                        \
    __builtin_amdgcn_sched_barrier(0);                   \
  } while (0)

static __device__ __forceinline__ u16 f2b(float f) {
  uint32_t b = __float_as_uint(f);
  return (u16)((b + 0x7fffu + ((b >> 16) & 1u)) >> 16);  // RNE
}
static __device__ __forceinline__ uint64_t pack4(float4 v) {
  return (uint64_t)f2b(v.x) | ((uint64_t)f2b(v.y) << 16) |
         ((uint64_t)f2b(v.z) << 32) | ((uint64_t)f2b(v.w) << 48);
}
static __device__ __forceinline__ float b2f(u16 u) {
  return __uint_as_float(((uint32_t)u) << 16);
}
static __device__ __forceinline__ float sigm(float x) {
  return 1.0f / (1.0f + __expf(-x));
}
static __device__ __forceinline__ float tanh_(float x) {
  float e = __expf(2.0f * x);
  return 1.0f - 2.0f / (e + 1.0f);
}

// ---------------------------------------------------------------- prep kernels
__global__ __launch_bounds__(256) void transpose_w(const float* __restrict__ Wih,
                                                   const float* __restrict__ Whh,
                                                   u16* __restrict__ Tih,
                                                   u16* __restrict__ Thh) {
  __shared__ float tile[64][65];
  const float* src = blockIdx.z ? Whh : Wih;
  u16* dst = blockIdx.z ? Thh : Tih;
  int k0 = blockIdx.y * 64, n0 = blockIdx.x * 64;
  int tid = threadIdx.x;
#pragma unroll
  for (int i = 0; i < 16; ++i) {
    int idx = i * 256 + tid;
    int kl = idx >> 6, nl = idx & 63;
    tile[kl][nl] = src[(size_t)(k0 + kl) * 4096 + n0 + nl];
  }
  __syncthreads();
#pragma unroll
  for (int i = 0; i < 16; ++i) {
    int idx = i * 256 + tid;
    int nl = idx >> 6, kl = idx & 63;
    dst[(size_t)(n0 + nl) * 1024 + k0 + kl] = f2b(tile[kl][nl]);
  }
}

// h0 [64][1024] f32 -> tagged words (tag 0) in h_tag buf 1
__global__ __launch_bounds__(256) void convert_h0(const float* __restrict__ h0,
                                                  uint64_t* __restrict__ dst) {
  int i = blockIdx.x * 256 + threadIdx.x;  // 32768 words
  float2 v = ((const float2*)h0)[i];
  uint32_t pair = (uint32_t)f2b(v.x) | ((uint32_t)f2b(v.y) << 16);
  dst[i] = (uint64_t)pair;  // tag = 0
}

// one x window [64*64*1024] f32 -> bf16 (paired u32 stores)
__global__ __launch_bounds__(256) void convert_xwin(const float* __restrict__ src,
                                                    u16* __restrict__ dst) {
  int i = blockIdx.x * 256 + threadIdx.x;  // 2097152 u32 words
  float2 v = ((const float2*)src)[i];
  ((uint32_t*)dst)[i] = (uint32_t)f2b(v.x) | ((uint32_t)f2b(v.y) << 16);
}

// ------------------------------------------------------------------- big GEMM
// C[M][4096] bf16 = A[M][1024] f32 @ Bt[4096][1024]^T + bias. (window 0 only)
__global__ __launch_bounds__(256) void gemm_xg(const float* __restrict__ A,
                                               const u16* __restrict__ Bt,
                                               const float* __restrict__ bias,
                                               u16* __restrict__ C) {
  __shared__ u16 sA[2][128 * 32];
  __shared__ u16 sB[2][128 * 32];
  const int tid = threadIdx.x;
  const int wave = tid >> 6, lane = tid & 63;
  const int bx = blockIdx.x, by = blockIdx.y;
  const int wr = wave >> 1, wc = wave & 1;
  const int lm = lane & 15, ko = (lane >> 4) * 8;

  const int ar = lane >> 1, ac = (lane & 1) * 16;
  const float* gA = A + (size_t)(by * 128 + wave * 32 + ar) * 1024 + ac;
  const u16* gB = Bt + (size_t)(bx * 128 + wave * 32 + (lane >> 2)) * 1024 + (lane & 3) * 8;
  const int bidx = wave * 1024 + (lane >> 2) * 32 + (lane & 3) * 8;

  f32x4 acc[4][4] = {};

  auto stage = [&](int kt, int buf) {
    const u16* gb = gB + kt * 32;
    bf16x8 b0 = *(const bf16x8*)gb;
    bf16x8 b1 = *(const bf16x8*)(gb + 16 * 1024);
    *(bf16x8*)&sB[buf][bidx] = b0;
    *(bf16x8*)&sB[buf][bidx + 512] = b1;
    const float* ga = gA + kt * 32;
    float4 v0 = *(const float4*)(ga + 0);
    float4 v1 = *(const float4*)(ga + 4);
    float4 v2 = *(const float4*)(ga + 8);
    float4 v3 = *(const float4*)(ga + 12);
    uint64_t* la = (uint64_t*)&sA[buf][wave * 1024 + ar * 32 + ac];
    la[0] = pack4(v0);
    la[1] = pack4(v1);
    la[2] = pack4(v2);
    la[3] = pack4(v3);
  };

  stage(0, 0);
  __syncthreads();
  int p = 0;
  for (int kt = 0; kt < 32; ++kt) {
    if (kt < 31) stage(kt + 1, p ^ 1);
    bf16x8 af[4], bfv[4];
#pragma unroll
    for (int i = 0; i < 4; ++i)
      af[i] = *(const bf16x8*)&sA[p][(wr * 64 + i * 16 + lm) * 32 + ko];
#pragma unroll
    for (int j = 0; j < 4; ++j)
      bfv[j] = *(const bf16x8*)&sB[p][(wc * 64 + j * 16 + lm) * 32 + ko];
#pragma unroll
    for (int i = 0; i < 4; ++i)
#pragma unroll
      for (int j = 0; j < 4; ++j)
        acc[i][j] = __builtin_amdgcn_mfma_f32_16x16x32_bf16(af[i], bfv[j], acc[i][j], 0, 0, 0);
    __syncthreads();
    p ^= 1;
  }

  float bj[4];
#pragma unroll
  for (int j = 0; j < 4; ++j)
    bj[j] = bias[bx * 128 + wc * 64 + j * 16 + lm];
#pragma unroll
  for (int i = 0; i < 4; ++i) {
    int row = by * 128 + wr * 64 + i * 16 + (lane >> 4) * 4;
#pragma unroll
    for (int j = 0; j < 4; ++j) {
      int col = bx * 128 + wc * 64 + j * 16 + lm;
#pragma unroll
      for (int r = 0; r < 4; ++r)
        C[(size_t)(row + r) * 4096 + col] = f2b(acc[i][j][r] + bj[j]);
    }
  }
}

// --------------------------------------- persistent tagged-h recurrence
// Grid 256 blocks (1/CU), block 512 (8 waves). bid: un=bid&63, bq=bid>>6.
// Recurrence mapping identical to R15/R19. Fused gemm: block tile = rows
// [rt*128,+128) x cols [ct*512,+512) of xg(w+1) (rt=bid>>3, ct=bid&7);
// subtile id = (ts>>1)*8+wave; K chain split over step pair (ts&1).
__global__ __launch_bounds__(512, 1) void recur_pers(
    const u16* __restrict__ xg,        // [64][64][4096] bf16 window w (read)
    const u16* __restrict__ whh_t,     // [4096][1024] bf16
    uint64_t* __restrict__ h_tag,      // [2][64][512] tagged words
    float* __restrict__ c_st,          // [64][1024] f32
    float* __restrict__ out_h,         // [512][64][1024] f32
    float* __restrict__ out_hT, float* __restrict__ out_cT,
    int t0, int W,
    u16* __restrict__ xg_wr,           // xg window w+1 (write; null=skip)
    const u16* __restrict__ x_rd,      // x_bf window w+1 (A operand)
    const u16* __restrict__ wih_t,     // [4096][1024] bf16 (B operand)
    const float* __restrict__ bias,    // [4096]
    const float* __restrict__ xcv_src, // x f32 window w+2 (null=skip)
    u16* __restrict__ xcv_dst) {       // x_bf window w+2
  __shared__ float xchg[8][16][68];  // 34.8KB, padded

  const int tid = threadIdx.x;
  const int wave = tid >> 6, lane = tid & 63;
  const int bid = blockIdx.x;
  const int un = bid & 63;
  const int bq = bid >> 6;
  const int lm = lane & 15, hi = lane >> 4;

  // ---- W_hh B-frags: bfr[kk][nt]; row = nt*1024 + un*16 + lm ----
  bf16x8 bfr[4][4];
#pragma unroll
  for (int nt = 0; nt < 4; ++nt) {
    const u16* bp = whh_t + (size_t)(nt * 1024 + un * 16 + lm) * 1024 + wave * 128 + hi * 8;
#pragma unroll
    for (int kk = 0; kk < 4; ++kk) bfr[kk][nt] = *(const bf16x8*)(bp + kk * 32);
  }

  // ---- epilogue ownership: tid<256 -> (row r_b, unit u) ----
  const int r_b = tid >> 4, u = tid & 15;
  const int b = bq * 16 + r_b;
  const int unit = un * 16 + u;
  float c_val = (tid < 256) ? c_st[b * 1024 + unit] : 0.f;

  const int b_row = bq * 16 + lm;  // A-frag batch row for this lane

  // ---- fused-gemm state ----
  const int rt = bid >> 3, ct = bid & 7;
  f32x4 gacc0 = {}, gacc1 = {};

  for (int ts = 0; ts < W; ++ts) {
    const int t = t0 + ts;

    // ---- xg loads first (independent; complete under the poll) ----
    u16 xr0 = 0, xr1 = 0, xr2 = 0, xr3 = 0;
    if (tid < 256) {
      const u16* xgp = xg + ((size_t)ts * 64 + b) * 4096 + unit;
      xr0 = xgp[0];
      xr1 = xgp[1024];
      xr2 = xgp[2048];
      xr3 = xgp[3072];
    }

    // ---- poll the 16 tagged words of my A-frag (tag >= t) ----
    const uint64_t* hb = h_tag + ((size_t)((t - 1) & 1) * 64 + b_row) * 512 +
                         wave * 64 + hi * 4;
    uint64_t wbuf[16];
    {
      uint32_t spin = 0;
      bool ok = false;
      for (; spin < (1u << 15); ++spin) {  // bounded: never wedge
#pragma unroll
        for (int kk = 0; kk < 4; ++kk)
#pragma unroll
          for (int j = 0; j < 4; ++j)
            wbuf[kk * 4 + j] = __hip_atomic_load(hb + kk * 16 + j, __ATOMIC_RELAXED,
                                                 __HIP_MEMORY_SCOPE_AGENT);
        bool good = true;
#pragma unroll
        for (int i = 0; i < 16; ++i)
          good &= ((uint32_t)(wbuf[i] >> 32) >= (uint32_t)t);
        if (__all(good)) { ok = true; break; }
        __builtin_amdgcn_s_sleep(1);
      }
      if (!ok && lane == 0)  // sentinel: absmax ~1e6 => protocol stall
        out_h[(size_t)t * 65536 + bid] = 1.0e6f;
    }

    // ---- extract payload -> 4 A-frags; 16 MFMAs (4 chains of 4) ----
    f32x4 acc[4] = {};
#pragma unroll
    for (int kk = 0; kk < 4; ++kk) {
      u64x2 v;
      v.x = (uint64_t)(uint32_t)wbuf[kk * 4 + 0] |
            ((uint64_t)(uint32_t)wbuf[kk * 4 + 1] << 32);
      v.y = (uint64_t)(uint32_t)wbuf[kk * 4 + 2] |
            ((uint64_t)(uint32_t)wbuf[kk * 4 + 3] << 32);
      bf16x8 a = __builtin_bit_cast(bf16x8, v);
#pragma unroll
      for (int nt = 0; nt < 4; ++nt)
        acc[nt] = __builtin_amdgcn_mfma_f32_16x16x32_bf16(a, bfr[kk][nt], acc[nt], 0, 0, 0);
    }
    {
      int crow = hi * 4;  // C layout: col=lane&15, row=(lane>>4)*4+r
#pragma unroll
      for (int nt = 0; nt < 4; ++nt)
#pragma unroll
        for (int r = 0; r < 4; ++r) xchg[wave][crow + r][nt * 16 + lm] = acc[nt][r];
    }
    BAR_LDS();  // xchg writes visible (no vmcnt drain)

    if (tid < 256) {
      float raw[4];
#pragma unroll
      for (int g = 0; g < 4; ++g) {
        int c = g * 16 + u;
        float s = xchg[0][r_b][c];
#pragma unroll
        for (int w = 1; w < 8; ++w) s += xchg[w][r_b][c];
        raw[g] = s;
      }
      float ig = sigm(raw[0] + b2f(xr0));
      float fg = sigm(raw[1] + b2f(xr1));
      float gg = tanh_(raw[2] + b2f(xr2));
      float og = sigm(raw[3] + b2f(xr3));
      c_val = fg * c_val + ig * gg;
      float h_new = og * tanh_(c_val);
      uint32_t mine = f2b(h_new);
      uint32_t other = __shfl_xor(mine, 1);
      if ((u & 1) == 0) {
        uint64_t word = (uint64_t)(mine | (other << 16)) | ((uint64_t)(uint32_t)(t + 1) << 32);
        __hip_atomic_store(
            h_tag + ((size_t)(t & 1) * 64 + b) * 512 + (unit >> 1), word,
            __ATOMIC_RELAXED, __HIP_MEMORY_SCOPE_AGENT);
      }
      out_h[(size_t)t * 65536 + (size_t)b * 1024 + unit] = h_new;
      if (t == 511) {
        out_hT[b * 1024 + unit] = h_new;
        out_cT[b * 1024 + unit] = c_val;
      }
    }

    // ---- fused gemm slice: next window's xg (productive backoff) ----
    if (xg_wr) {
      const int p2 = ts >> 1, half = ts & 1;
      const int id = p2 * 8 + wave;
      const int rsub = rt * 128 + (id >> 5) * 16;
      const int gcol = ct * 512 + (id & 31) * 16 + lm;
      const u16* ax = x_rd + (size_t)(rsub + lm) * 1024 + half * 512 + hi * 8;
      const u16* bw = wih_t + (size_t)gcol * 1024 + half * 512 + hi * 8;
      if (!half) { gacc0 = (f32x4){}; gacc1 = (f32x4){}; }
#pragma unroll
      for (int kk = 0; kk < 16; kk += 2) {
        bf16x8 a0 = *(const bf16x8*)(ax + kk * 32);
        bf16x8 b0 = *(const bf16x8*)(bw + kk * 32);
        bf16x8 a1 = *(const bf16x8*)(ax + (kk + 1) * 32);
        bf16x8 b1 = *(const bf16x8*)(bw + (kk + 1) * 32);
        gacc0 = __builtin_amdgcn_mfma_f32_16x16x32_bf16(a0, b0, gacc0, 0, 0, 0);
        gacc1 = __builtin_amdgcn_mfma_f32_16x16x32_bf16(a1, b1, gacc1, 0, 0, 0);
      }
      if (half) {
        float bj = bias[gcol];
        f32x4 s = gacc0 + gacc1;
        int crow = rsub + hi * 4;
#pragma unroll
        for (int r = 0; r < 4; ++r)
          xg_wr[(size_t)(crow + r) * 4096 + gcol] = f2b(s[r] + bj);
      }
    }
    // ---- x convert slice: window w+2 f32 -> bf16 (0.5 elem/thread/step) ----
    if (xcv_src && !(ts & 1)) {
      int idx = bid * 16384 + (ts >> 1) * 512 + tid;
      xcv_dst[idx] = f2b(xcv_src[idx]);
    }

    BAR_LDS();  // xchg WAR
  }

  if (tid < 256) c_st[b * 1024 + unit] = c_val;
}

// -------------------------------------------------------------------- launch
extern "C" void kernel_launch(void* const* d_in, const int* in_sizes, int n_in,
                              void* d_out, int out_size, void* d_ws, size_t ws_size,
                              hipStream_t stream) {
  const float* x = (const float*)d_in[0];
  const float* h0 = (const float*)d_in[1];
  const float* c0 = (const float*)d_in[2];
  const float* wih = (const float*)d_in[3];
  const float* whh = (const float*)d_in[4];
  const float* bias = (const float*)d_in[5];

  float* out = (float*)d_out;
  float* out_h = out;                              // [512][64][1024]
  float* out_hT = out + (size_t)512 * 64 * 1024;   // [64][1024]
  float* out_cT = out_hT + 64 * 1024;              // [64][1024]

  const size_t MB = 1024 * 1024;
  const size_t fused_need = 16 * MB                 // wih_t + whh_t
                            + 64 * MB               // xgA + xgB
                            + 16 * MB               // x_bf dbuf
                            + (size_t)2 * 64 * 512 * 8   // h_tag
                            + (size_t)64 * 1024 * 4;     // c_state
  const bool fused = ws_size >= fused_need;

  char* ws = (char*)d_ws;
  u16* wih_t = (u16*)ws;   ws += (size_t)4096 * 1024 * 2;  // 8MB
  u16* whh_t = (u16*)ws;   ws += (size_t)4096 * 1024 * 2;  // 8MB

  if (fused) {
    u16* xgA = (u16*)ws;   ws += (size_t)64 * 64 * 4096 * 2;  // 32MB
    u16* xgB = (u16*)ws;   ws += (size_t)64 * 64 * 4096 * 2;  // 32MB
    u16* xb0 = (u16*)ws;   ws += (size_t)64 * 64 * 1024 * 2;  // 8MB
    u16* xb1 = (u16*)ws;   ws += (size_t)64 * 64 * 1024 * 2;  // 8MB
    uint64_t* h_tag = (uint64_t*)ws; ws += (size_t)2 * 64 * 512 * 8;
    float* c_st = (float*)ws;

    hipMemsetAsync(h_tag, 0, (size_t)2 * 64 * 512 * 8, stream);
    convert_h0<<<128, 256, 0, stream>>>(h0, h_tag + (size_t)64 * 512);
    hipMemcpyAsync(c_st, c0, (size_t)64 * 1024 * 4, hipMemcpyDeviceToDevice, stream);
    transpose_w<<<dim3(64, 16, 2), 256, 0, stream>>>(wih, whh, wih_t, whh_t);
    convert_xwin<<<8192, 256, 0, stream>>>(x + (size_t)64 * 65536, xb1);  // window 1
    gemm_xg<<<dim3(32, 32), 256, 0, stream>>>(x, wih_t, bias, xgA);      // window 0

    for (int w = 0; w < 8; ++w) {
      int t0 = w * 64, Wc = 64;
      const u16* xg_rd = (w & 1) ? xgB : xgA;
      u16* xg_w = (w < 7) ? ((w & 1) ? xgA : xgB) : nullptr;
      const u16* x_rd = ((w + 1) & 1) ? xb1 : xb0;   // x_bf window w+1
      const float* xcv_s = (w < 6) ? (x + (size_t)(t0 + 128) * 65536) : nullptr;
      u16* xcv_d = (w & 1) ? xb1 : xb0;              // x_bf window w+2
      void* args[] = {(void*)&xg_rd, (void*)&whh_t, (void*)&h_tag, (void*)&c_st,
                      (void*)&out_h, (void*)&out_hT, (void*)&out_cT,
                      (void*)&t0,    (void*)&Wc,
                      (void*)&xg_w,  (void*)&x_rd,  (void*)&wih_t, (void*)&bias,
                      (void*)&xcv_s, (void*)&xcv_d};
      hipLaunchCooperativeKernel((const void*)recur_pers, dim3(256), dim3(512), args, 0,
                                 stream);
    }
  } else {
    // fallback = R19 path (proven): per-window standalone gemm, no fusion
    int W = 64;
    const size_t fixed = 16 * MB + (size_t)2 * 64 * 512 * 8 + (size_t)64 * 1024 * 4;
    while (W > 4 && fixed + (size_t)W * 64 * 4096 * 2 > ws_size) W >>= 2;
    u16* xg = (u16*)ws;    ws += (size_t)W * 64 * 4096 * 2;
    uint64_t* h_tag = (uint64_t*)ws; ws += (size_t)2 * 64 * 512 * 8;
    float* c_st = (float*)ws;

    hipMemsetAsync(h_tag, 0, (size_t)2 * 64 * 512 * 8, stream);
    convert_h0<<<128, 256, 0, stream>>>(h0, h_tag + (size_t)64 * 512);
    hipMemcpyAsync(c_st, c0, (size_t)64 * 1024 * 4, hipMemcpyDeviceToDevice, stream);
    transpose_w<<<dim3(64, 16, 2), 256, 0, stream>>>(wih, whh, wih_t, whh_t);

    for (int t0 = 0; t0 < 512; t0 += W) {
      gemm_xg<<<dim3(32, W / 2), 256, 0, stream>>>(x + (size_t)t0 * 64 * 1024, wih_t, bias, xg);
      int t0c = t0, Wc = W;
      u16* xg_w = nullptr;
      const u16* x_rd = nullptr;
      const float* xcv_s = nullptr;
      u16* xcv_d = nullptr;
      void* args[] = {(void*)&xg,    (void*)&whh_t, (void*)&h_tag, (void*)&c_st,
                      (void*)&out_h, (void*)&out_hT, (void*)&out_cT,
                      (void*)&t0c,   (void*)&Wc,
                      (void*)&xg_w,  (void*)&x_rd,  (void*)&wih_t, (void*)&bias,
                      (void*)&xcv_s, (void*)&xcv_d};
      hipLaunchCooperativeKernel((const void*)recur_pers, dim3(256), dim3(512), args, 0,
                                 stream);
    }
  }
}